// Round 1
// baseline (11188.217 us; speedup 1.0000x reference)
//
#include <hip/hip_runtime.h>

#define D      1024
#define BSZ    512
#define MC     256
#define NBK    64
#define NPAN   16
#define N_ROUNDS 3
#define MAXIT  30
#define TOLV   0.01f
#define RHOV   3.0f
#define XRHOV  0.5f
#define SPLITK 4

// ---------------- shared tile FMA (64x64 tile, 4x4 per thread) ----------------
__device__ __forceinline__ void tile_fma(float (*As)[68], float (*Bs)[68],
                                         float acc[4][4], const int tx, const int ty) {
#pragma unroll 8
  for (int kk = 0; kk < 64; ++kk) {
    const float4 a4 = *(const float4*)(&As[kk][ty * 4]);
    const float4 b4 = *(const float4*)(&Bs[kk][tx * 4]);
    const float a0 = a4.x, a1 = a4.y, a2 = a4.z, a3 = a4.w;
    const float b0 = b4.x, b1 = b4.y, b2 = b4.z, b3 = b4.w;
    acc[0][0] = fmaf(a0, b0, acc[0][0]); acc[0][1] = fmaf(a0, b1, acc[0][1]);
    acc[0][2] = fmaf(a0, b2, acc[0][2]); acc[0][3] = fmaf(a0, b3, acc[0][3]);
    acc[1][0] = fmaf(a1, b0, acc[1][0]); acc[1][1] = fmaf(a1, b1, acc[1][1]);
    acc[1][2] = fmaf(a1, b2, acc[1][2]); acc[1][3] = fmaf(a1, b3, acc[1][3]);
    acc[2][0] = fmaf(a2, b0, acc[2][0]); acc[2][1] = fmaf(a2, b1, acc[2][1]);
    acc[2][2] = fmaf(a2, b2, acc[2][2]); acc[2][3] = fmaf(a2, b3, acc[2][3]);
    acc[3][0] = fmaf(a3, b0, acc[3][0]); acc[3][1] = fmaf(a3, b1, acc[3][1]);
    acc[3][2] = fmaf(a3, b2, acc[3][2]); acc[3][3] = fmaf(a3, b3, acc[3][3]);
  }
}

// ---------------- misc init ----------------
__global__ void k_init(int* __restrict__ perm, float* __restrict__ err) {
  const int i = blockIdx.x * 256 + threadIdx.x;
  if (i < D) perm[i] = i;
  if (i < N_ROUNDS * MAXIT) err[i] = -1.0f;  // sentinel: "iteration never ran"
}

// F = copy(L); Ybuf = CT = (L*diag(Lam))^T, i.e. CT[j][i] = Lam[j]*L[i][j]
__global__ __launch_bounds__(256) void k_prep(const float* __restrict__ L,
                                              const float* __restrict__ Lam,
                                              float* __restrict__ F,
                                              float* __restrict__ Ybuf,
                                              float* __restrict__ CT) {
  __shared__ float tile[64][65];
  const int bi = blockIdx.y, bj = blockIdx.x;
  const int tx = threadIdx.x & 63, ty4 = threadIdx.x >> 6;
  const int i0 = bi * 64, j0 = bj * 64;
  for (int r = ty4; r < 64; r += 4) {
    const float v = L[(size_t)(i0 + r) * D + j0 + tx];
    F[(size_t)(i0 + r) * D + j0 + tx] = v;
    tile[r][tx] = v;
  }
  __syncthreads();
  for (int r = ty4; r < 64; r += 4) {
    const int j = j0 + r;
    const float val = Lam[j] * tile[tx][r];
    Ybuf[(size_t)j * D + i0 + tx] = val;
    CT[(size_t)j * D + i0 + tx] = val;
  }
}

// ---------------- LU with block-local partial pivoting ----------------
__global__ __launch_bounds__(256) void k_lu_diag(float* __restrict__ F,
                                                 int* __restrict__ perm, int k) {
  __shared__ float blk[64][65];
  __shared__ int pr_sh;
  const int tid = threadIdx.x;
  const int c0 = k * NBK;
  for (int e = tid; e < 4096; e += 256) {
    const int r = e >> 6, c = e & 63;
    blk[r][c] = F[(size_t)(c0 + r) * D + c0 + c];
  }
  __syncthreads();
  for (int j = 0; j < 64; ++j) {
    if (tid < 64) {  // pivot search among the 64 band rows
      float v = (tid >= j) ? fabsf(blk[tid][j]) : -1.0f;
      int ridx = tid;
      for (int off = 32; off > 0; off >>= 1) {
        const float ov = __shfl_down(v, off);
        const int oi = __shfl_down(ridx, off);
        if (ov > v) { v = ov; ridx = oi; }
      }
      if (tid == 0) pr_sh = ridx;
    }
    __syncthreads();
    const int pr = pr_sh;
    if (pr != j) {
      if (tid < 64) { const float a = blk[j][tid], b = blk[pr][tid]; blk[j][tid] = b; blk[pr][tid] = a; }
      if (tid == 0) { const int t = perm[c0 + j]; perm[c0 + j] = perm[c0 + pr]; perm[c0 + pr] = t; }
    }
    __syncthreads();
    if (pr != j) {  // swap the rest of the two full rows in global memory
      for (int c = tid; c < D; c += 256) {
        if (c >= c0 && c < c0 + 64) continue;
        const float a = F[(size_t)(c0 + j) * D + c], b = F[(size_t)(c0 + pr) * D + c];
        F[(size_t)(c0 + j) * D + c] = b;
        F[(size_t)(c0 + pr) * D + c] = a;
      }
    }
    const float inv = 1.0f / blk[j][j];
    const int r = tid >> 2, l4 = tid & 3;
    if (r > j) {
      const float lval = blk[r][j] * inv;
      if (l4 == 0) blk[r][j] = lval;
      for (int c = j + 1 + l4; c < 64; c += 4)
        blk[r][c] = fmaf(-lval, blk[j][c], blk[r][c]);
    }
    __syncthreads();
  }
  for (int e = tid; e < 4096; e += 256) {
    const int r = e >> 6, c = e & 63;
    F[(size_t)(c0 + r) * D + c0 + c] = blk[r][c];
  }
}

// L21 = A21 * U11^-1  (row-parallel forward substitution from the right)
__global__ __launch_bounds__(256) void k_l21(float* __restrict__ F, int k) {
  const int c0 = k * NBK;
  const int row0 = c0 + NBK;
  const int nrows = D - row0;
  __shared__ float U[64][65];
  const int tid = threadIdx.x;
  for (int e = tid; e < 4096; e += 256) { const int r = e >> 6, c = e & 63; U[r][c] = F[(size_t)(c0 + r) * D + c0 + c]; }
  __syncthreads();
  const int r = blockIdx.x * 256 + tid;
  if (r >= nrows) return;
  float* Arow = &F[(size_t)(row0 + r) * D + c0];
  float x[64];
#pragma unroll
  for (int jj = 0; jj < 64; ++jj) {
    float s0 = 0.f, s1 = 0.f, s2 = 0.f, s3 = 0.f;
#pragma unroll
    for (int i = 0; i + 3 < jj; i += 4) {
      s0 = fmaf(x[i], U[i][jj], s0);
      s1 = fmaf(x[i + 1], U[i + 1][jj], s1);
      s2 = fmaf(x[i + 2], U[i + 2][jj], s2);
      s3 = fmaf(x[i + 3], U[i + 3][jj], s3);
    }
#pragma unroll
    for (int i = (jj / 4) * 4; i < jj; ++i) s0 = fmaf(x[i], U[i][jj], s0);
    const float a = Arow[jj] - ((s0 + s1) + (s2 + s3));
    x[jj] = a / U[jj][jj];
    Arow[jj] = x[jj];
  }
}

// U12 = Lam11^-1 * A12 (unit lower), column-parallel
__global__ __launch_bounds__(256) void k_trsm_row(float* __restrict__ F, int k) {
  const int c0 = k * NBK;
  const int colstart = c0 + NBK;
  const int ncols = D - colstart;
  __shared__ float Lw[64][65];
  const int tid = threadIdx.x;
  for (int e = tid; e < 4096; e += 256) { const int r = e >> 6, c = e & 63; Lw[r][c] = F[(size_t)(c0 + r) * D + c0 + c]; }
  __syncthreads();
  const int cidx = blockIdx.x * 256 + tid;
  if (cidx >= ncols) return;
  const int col = colstart + cidx;
  float x[64];
#pragma unroll
  for (int i = 0; i < 64; ++i) {
    float s0 = 0.f, s1 = 0.f, s2 = 0.f, s3 = 0.f;
#pragma unroll
    for (int j = 0; j + 3 < i; j += 4) {
      s0 = fmaf(Lw[i][j], x[j], s0);
      s1 = fmaf(Lw[i][j + 1], x[j + 1], s1);
      s2 = fmaf(Lw[i][j + 2], x[j + 2], s2);
      s3 = fmaf(Lw[i][j + 3], x[j + 3], s3);
    }
#pragma unroll
    for (int j = (i / 4) * 4; j < i; ++j) s0 = fmaf(Lw[i][j], x[j], s0);
    const float a = F[(size_t)(c0 + i) * D + col] - ((s0 + s1) + (s2 + s3));
    x[i] = a;
    F[(size_t)(c0 + i) * D + col] = a;
  }
}

// A22 -= L21 * U12  (K=64)
__global__ __launch_bounds__(256) void k_gemm_nn_update(float* __restrict__ F, int k) {
  const int c0 = k * NBK;
  const int o = c0 + NBK;
  __shared__ alignas(16) float As[64][68];
  __shared__ alignas(16) float Bs[64][68];
  const int tid = threadIdx.x;
  const int cc0 = o + blockIdx.x * 64;
  const int r0 = o + blockIdx.y * 64;
  for (int e = tid; e < 4096; e += 256) {
    const int r = e >> 6, c = e & 63;
    As[c][r] = F[(size_t)(r0 + r) * D + c0 + c];
    Bs[r][c] = F[(size_t)(c0 + r) * D + cc0 + c];
  }
  __syncthreads();
  float acc[4][4] = {};
  tile_fma(As, Bs, acc, tid & 15, tid >> 4);
  const int tx = tid & 15, ty = tid >> 4;
  for (int i = 0; i < 4; ++i)
    for (int j = 0; j < 4; ++j)
      F[(size_t)(r0 + ty * 4 + i) * D + cc0 + tx * 4 + j] -= acc[i][j];
}

// forward diag solve: Z_k = (U_kk^T)^-1 RHS_k  (lower, non-unit diag)
__global__ __launch_bounds__(256) void k_fsolve_diag(const float* __restrict__ F,
                                                     float* __restrict__ Y, int k) {
  __shared__ float T[64][65];  // T[i][j] = U[c0+j][c0+i]
  const int tid = threadIdx.x;
  const int c0 = k * NBK;
  for (int e = tid; e < 4096; e += 256) { const int r = e >> 6, c = e & 63; T[c][r] = F[(size_t)(c0 + r) * D + c0 + c]; }
  __syncthreads();
  const int col = blockIdx.x * 256 + tid;
  float x[64];
#pragma unroll
  for (int i = 0; i < 64; ++i) {
    float s0 = 0.f, s1 = 0.f, s2 = 0.f, s3 = 0.f;
#pragma unroll
    for (int j = 0; j + 3 < i; j += 4) {
      s0 = fmaf(T[i][j], x[j], s0);
      s1 = fmaf(T[i][j + 1], x[j + 1], s1);
      s2 = fmaf(T[i][j + 2], x[j + 2], s2);
      s3 = fmaf(T[i][j + 3], x[j + 3], s3);
    }
#pragma unroll
    for (int j = (i / 4) * 4; j < i; ++j) s0 = fmaf(T[i][j], x[j], s0);
    const float a = Y[(size_t)(c0 + i) * D + col] - ((s0 + s1) + (s2 + s3));
    x[i] = a / T[i][i];
    Y[(size_t)(c0 + i) * D + col] = x[i];
  }
}

// backward diag solve: Y_k = (Lam_kk^T)^-1 Z_k  (upper, unit diag)
__global__ __launch_bounds__(256) void k_bsolve_diag(const float* __restrict__ F,
                                                     float* __restrict__ Y, int k) {
  __shared__ float T[64][65];  // T[i][j] = Lam[c0+j][c0+i] (strict upper used)
  const int tid = threadIdx.x;
  const int c0 = k * NBK;
  for (int e = tid; e < 4096; e += 256) { const int r = e >> 6, c = e & 63; T[c][r] = F[(size_t)(c0 + r) * D + c0 + c]; }
  __syncthreads();
  const int col = blockIdx.x * 256 + tid;
  float x[64];
#pragma unroll
  for (int i = 63; i >= 0; --i) {
    float s0 = 0.f, s1 = 0.f, s2 = 0.f, s3 = 0.f;
#pragma unroll
    for (int j = i + 1; j + 3 < 64; j += 4) {
      s0 = fmaf(T[i][j], x[j], s0);
      s1 = fmaf(T[i][j + 1], x[j + 1], s1);
      s2 = fmaf(T[i][j + 2], x[j + 2], s2);
      s3 = fmaf(T[i][j + 3], x[j + 3], s3);
    }
#pragma unroll
    for (int j = i + 1 + (((63 - i) / 4) * 4); j < 64; ++j) s0 = fmaf(T[i][j], x[j], s0);
    const float a = Y[(size_t)(c0 + i) * D + col] - ((s0 + s1) + (s2 + s3));
    x[i] = a;
    Y[(size_t)(c0 + i) * D + col] = a;
  }
}

// RHS[r0.., :] -= (F panel-k rows as columns) @ Y_k : C[r][c] -= sum_j F[c0+j][r]*Y[c0+j][c]
__global__ __launch_bounds__(256) void k_gemm_tn_update(const float* __restrict__ F,
                                                        float* __restrict__ Y, int k, int rlo) {
  const int c0 = k * NBK;
  __shared__ alignas(16) float As[64][68];
  __shared__ alignas(16) float Bs[64][68];
  const int tid = threadIdx.x;
  const int cc0 = blockIdx.x * 64;
  const int r0 = rlo + blockIdx.y * 64;
  for (int e = tid; e < 4096; e += 256) {
    const int r = e >> 6, c = e & 63;
    As[r][c] = F[(size_t)(c0 + r) * D + r0 + c];
    Bs[r][c] = Y[(size_t)(c0 + r) * D + cc0 + c];
  }
  __syncthreads();
  float acc[4][4] = {};
  tile_fma(As, Bs, acc, tid & 15, tid >> 4);
  const int tx = tid & 15, ty = tid >> 4;
  for (int i = 0; i < 4; ++i)
    for (int j = 0; j < 4; ++j)
      Y[(size_t)(r0 + ty * 4 + i) * D + cc0 + tx * 4 + j] -= acc[i][j];
}

// scatter rows through perm: W[perm[i]][:] (+)= Y[i][:]
__global__ void k_scatter(const float* __restrict__ Y, float* __restrict__ Wm,
                          const int* __restrict__ perm, int add) {
  const int i = blockIdx.y;
  const int c = blockIdx.x * 256 + threadIdx.x;
  const int dst = perm[i];
  const float v = Y[(size_t)i * D + c];
  if (add) Wm[(size_t)dst * D + c] += v;
  else Wm[(size_t)dst * D + c] = v;
}

// residual: Y[i][c] = CT[i][c] - sum_k L[k][i]*W[k][c]
__global__ __launch_bounds__(256) void k_residual(const float* __restrict__ Lmat,
                                                  const float* __restrict__ Wm,
                                                  const float* __restrict__ CT,
                                                  float* __restrict__ Y) {
  __shared__ alignas(16) float As[64][68];
  __shared__ alignas(16) float Bs[64][68];
  const int tid = threadIdx.x;
  const int cc0 = blockIdx.x * 64;
  const int i0 = blockIdx.y * 64;
  float acc[4][4] = {};
  for (int kb = 0; kb < D; kb += 64) {
    for (int e = tid; e < 4096; e += 256) {
      const int r = e >> 6, c = e & 63;
      As[r][c] = Lmat[(size_t)(kb + r) * D + i0 + c];
      Bs[r][c] = Wm[(size_t)(kb + r) * D + cc0 + c];
    }
    __syncthreads();
    tile_fma(As, Bs, acc, tid & 15, tid >> 4);
    __syncthreads();
  }
  const int tx = tid & 15, ty = tid >> 4;
  for (int i = 0; i < 4; ++i)
    for (int j = 0; j < 4; ++j) {
      const size_t idx = (size_t)(i0 + ty * 4 + i) * D + cc0 + tx * 4 + j;
      Y[idx] = CT[idx] - acc[i][j];
    }
}

// t = -rho*c ; q = 0
__global__ void k_init_x(const float* __restrict__ cmat, float* __restrict__ t,
                         float* __restrict__ q) {
  const int e = blockIdx.x * 256 + threadIdx.x;
  t[e] = -RHOV * cmat[e];
  q[e] = 0.0f;
}

// round update: t[b][i] = yout[b][i] - xrho*sum_j yout[b][j]*W[j][i] - rho*c[b][i]; q=0
__global__ __launch_bounds__(256) void k_round(const float* __restrict__ yout,
                                               const float* __restrict__ Wm,
                                               const float* __restrict__ cmat,
                                               float* __restrict__ t, float* __restrict__ q) {
  __shared__ alignas(16) float As[64][68];
  __shared__ alignas(16) float Bs[64][68];
  const int tid = threadIdx.x;
  const int i0 = blockIdx.x * 64;
  const int b0 = blockIdx.y * 64;
  float acc[4][4] = {};
  for (int kb = 0; kb < D; kb += 64) {
    for (int e = tid; e < 4096; e += 256) {
      const int r = e >> 6, c = e & 63;
      As[c][r] = yout[(size_t)(b0 + r) * D + kb + c];
      Bs[r][c] = Wm[(size_t)(kb + r) * D + i0 + c];
    }
    __syncthreads();
    tile_fma(As, Bs, acc, tid & 15, tid >> 4);
    __syncthreads();
  }
  const int tx = tid & 15, ty = tid >> 4;
  for (int i = 0; i < 4; ++i)
    for (int j = 0; j < 4; ++j) {
      const int b = b0 + ty * 4 + i, col = i0 + tx * 4 + j;
      const float v = yout[(size_t)b * D + col] - XRHOV * acc[i][j] - RHOV * cmat[(size_t)b * D + col];
      t[(size_t)b * D + col] = v;
      q[(size_t)b * D + col] = 0.0f;
    }
}

__device__ __forceinline__ int dyk_done_scan(const float* err, int base, int it) {
  for (int j = 0; j < it; ++j)
    if (err[base + j] < TOLV) return 1;
  return 0;
}

// Dykstra kernel A: u_part[z] = (t @ A^T) partial over K-range z
__global__ __launch_bounds__(256) void k_dyk_A(const float* __restrict__ t,
                                               const float* __restrict__ Amat,
                                               float* __restrict__ u_part,
                                               const float* __restrict__ err, int base, int it) {
  __shared__ int s_done;
  if (threadIdx.x == 0) s_done = dyk_done_scan(err, base, it);
  __syncthreads();
  if (s_done) return;
  __shared__ alignas(16) float As[64][68];
  __shared__ alignas(16) float Bs[64][68];
  const int tid = threadIdx.x;
  const int m0 = blockIdx.x * 64;
  const int b0 = blockIdx.y * 64;
  const int z = blockIdx.z;
  float acc[4][4] = {};
  for (int kb = z * (D / SPLITK); kb < (z + 1) * (D / SPLITK); kb += 64) {
    for (int e = tid; e < 4096; e += 256) {
      const int r = e >> 6, c = e & 63;
      As[c][r] = t[(size_t)(b0 + r) * D + kb + c];
      Bs[c][r] = Amat[(size_t)(m0 + r) * D + kb + c];
    }
    __syncthreads();
    tile_fma(As, Bs, acc, tid & 15, tid >> 4);
    __syncthreads();
  }
  const int tx = tid & 15, ty = tid >> 4;
  for (int i = 0; i < 4; ++i)
    for (int j = 0; j < 4; ++j)
      u_part[(size_t)z * BSZ * MC + (size_t)(b0 + ty * 4 + i) * MC + m0 + tx * 4 + j] = acc[i][j];
}

// Dykstra kernel B: y = t - u @ AA^T, plus all elementwise updates + err reduction
__global__ __launch_bounds__(256) void k_dyk_B(float* __restrict__ t, float* __restrict__ q,
                                               float* __restrict__ yout,
                                               const float* __restrict__ u_part,
                                               const float* __restrict__ AAm,
                                               const float* __restrict__ bvec,
                                               float* __restrict__ err, int base, int it) {
  __shared__ int s_done;
  if (threadIdx.x == 0) s_done = dyk_done_scan(err, base, it);
  __syncthreads();
  if (s_done) return;
  __shared__ alignas(16) float As[64][68];
  __shared__ alignas(16) float Bs[64][68];
  const int tid = threadIdx.x;
  const int d0 = blockIdx.x * 64;
  const int b0 = blockIdx.y * 64;
  float acc[4][4] = {};
  for (int kb = 0; kb < MC; kb += 64) {
    for (int e = tid; e < 4096; e += 256) {
      const int r = e >> 6, c = e & 63;
      const size_t ub = (size_t)(b0 + r) * MC + kb + c;
      const float uv = u_part[ub] + u_part[(size_t)BSZ * MC + ub] +
                       u_part[2 * (size_t)BSZ * MC + ub] + u_part[3 * (size_t)BSZ * MC + ub] -
                       bvec[kb + c];
      As[c][r] = uv;
      Bs[c][r] = AAm[(size_t)(d0 + r) * MC + kb + c];
    }
    __syncthreads();
    tile_fma(As, Bs, acc, tid & 15, tid >> 4);
    __syncthreads();
  }
  const int tx = tid & 15, ty = tid >> 4;
  float nmax = 0.0f;
  for (int i = 0; i < 4; ++i) {
    const int b = b0 + ty * 4 + i;
    for (int j = 0; j < 4; ++j) {
      const int d = d0 + tx * 4 + j;
      const size_t idx = (size_t)b * D + d;
      const float tv = t[idx];
      const float y = tv - acc[i][j];
      yout[idx] = y;
      const float qv = q[idx];
      const float yq = y + qv;
      const float xn = fmaxf(yq, 0.0f);
      t[idx] = xn + (tv - y);
      q[idx] = yq - xn;
      nmax = fmaxf(nmax, -y);
    }
  }
  __shared__ float red[256];
  red[tid] = nmax;
  __syncthreads();
  for (int s = 128; s > 0; s >>= 1) {
    if (tid < s) red[tid] = fmaxf(red[tid], red[tid + s]);
    __syncthreads();
  }
  if (tid == 0) atomicMax((int*)&err[base + it], __float_as_int(red[0]));
}

extern "C" void kernel_launch(void* const* d_in, const int* in_sizes, int n_in,
                              void* d_out, int out_size, void* d_ws, size_t ws_size,
                              hipStream_t stream) {
  (void)in_sizes; (void)n_in; (void)out_size; (void)ws_size;
  const float* cmat = (const float*)d_in[0];
  const float* Amat = (const float*)d_in[1];
  const float* bvec = (const float*)d_in[2];
  const float* AAm  = (const float*)d_in[3];
  const float* Lmat = (const float*)d_in[4];
  const float* Lam  = (const float*)d_in[5];
  float* yout = (float*)d_out;

  char* w = (char*)d_ws;
  float* F    = (float*)w; w += (size_t)D * D * 4;
  float* Ybuf = (float*)w; w += (size_t)D * D * 4;
  float* Wm   = (float*)w; w += (size_t)D * D * 4;
  float* CT   = (float*)w; w += (size_t)D * D * 4;
  float* t    = (float*)w; w += (size_t)BSZ * D * 4;
  float* q    = (float*)w; w += (size_t)BSZ * D * 4;
  float* up   = (float*)w; w += (size_t)SPLITK * BSZ * MC * 4;
  float* err  = (float*)w; w += 128 * 4;
  int* perm   = (int*)w;   w += D * 4;

  k_init<<<4, 256, 0, stream>>>(perm, err);
  k_prep<<<dim3(16, 16), 256, 0, stream>>>(Lmat, Lam, F, Ybuf, CT);

  // blocked LU with block-local partial pivoting
  for (int k = 0; k < NPAN; ++k) {
    k_lu_diag<<<1, 256, 0, stream>>>(F, perm, k);
    const int rem = D - (k + 1) * NBK;
    if (rem > 0) {
      k_l21<<<(rem + 255) / 256, 256, 0, stream>>>(F, k);
      k_trsm_row<<<(rem + 255) / 256, 256, 0, stream>>>(F, k);
      k_gemm_nn_update<<<dim3(rem / 64, rem / 64), 256, 0, stream>>>(F, k);
    }
  }

  // two solve passes (pass 1 = iterative refinement)
  for (int pass = 0; pass < 2; ++pass) {
    for (int k = 0; k < NPAN; ++k) {  // forward: Lower(U^T)
      k_fsolve_diag<<<4, 256, 0, stream>>>(F, Ybuf, k);
      const int rem = D - (k + 1) * NBK;
      if (rem > 0) k_gemm_tn_update<<<dim3(16, rem / 64), 256, 0, stream>>>(F, Ybuf, k, (k + 1) * NBK);
    }
    for (int k = NPAN - 1; k >= 0; --k) {  // backward: Upper(Lam^T), unit diag
      k_bsolve_diag<<<4, 256, 0, stream>>>(F, Ybuf, k);
      if (k > 0) k_gemm_tn_update<<<dim3(16, k), 256, 0, stream>>>(F, Ybuf, k, 0);
    }
    k_scatter<<<dim3(4, D), 256, 0, stream>>>(Ybuf, Wm, perm, pass);
    if (pass == 0) k_residual<<<dim3(16, 16), 256, 0, stream>>>(Lmat, Wm, CT, Ybuf);
  }

  // 3 rounds of step + Dykstra(30)
  k_init_x<<<(BSZ * D) / 256, 256, 0, stream>>>(cmat, t, q);
  for (int r = 0; r < N_ROUNDS; ++r) {
    if (r > 0) k_round<<<dim3(16, 8), 256, 0, stream>>>(yout, Wm, cmat, t, q);
    const int base = r * MAXIT;
    for (int it = 0; it < MAXIT; ++it) {
      k_dyk_A<<<dim3(MC / 64, BSZ / 64, SPLITK), 256, 0, stream>>>(t, Amat, up, err, base, it);
      k_dyk_B<<<dim3(D / 64, BSZ / 64), 256, 0, stream>>>(t, q, yout, up, AAm, bvec, err, base, it);
    }
  }
}